// Round 16
// baseline (236.110 us; speedup 1.0000x reference)
//
#include <hip/hip_runtime.h>
#include <hip/hip_bf16.h>

// MoE top-2: B=8,N=1024,C=768,E=8,H=1536. Tokens T=8192, assignments=16384.
typedef unsigned short u16;
typedef unsigned int u32;
typedef __bf16 bf16x8 __attribute__((ext_vector_type(8)));
typedef float f32x4 __attribute__((ext_vector_type(4)));

#define T_TOK 8192
#define C_DIM 768
#define E_DIM 8
#define H_DIM 1536
#define MAXBLK 136   // = 8 XCDs * 17; >= max Σ ceil(cnt[e]/128) = 135

// prep fusion: [0,2048) gating, [2048,4352) W1-transpose, [4352,6656) W2-transpose
#define PREP_GATE 2048
#define PREP_W1   2304
#define PREP_NBLK (PREP_GATE + 2 * PREP_W1)

// ---- ws layout (bytes) ----
#define XB_OFF   0ull                 // x bf16 [8192][768]           12,582,912
#define W1T_OFF  12582912ull          // W1^T bf16 [E][H][C]          18,874,368
#define W2T_OFF  31457280ull          // W2^T bf16 [E][C][H]          18,874,368
#define H_OFF    50331648ull          // h bf16 [16384][1536]         50,331,648
#define LIST_OFF 100663296ull         // int [E][8192] entry=2*tok+rank
#define WTS_OFF  100925440ull         // float [16384]
#define POSE_OFF 100990976ull         // int [16384]: (e<<14)|pos
#define CNT_OFF  101056512ull         // int [8]
#define OFFS_OFF 101056544ull         // int [8]
#define TOPS_OFF 101056576ull         // int [8192]: i1 | (i2<<4)      32,768
#define MTAB_OFF 101089344ull         // int [144]: (e<<8)|m_chunk     576
#define NBLK_OFF 101089920ull         // int [16]                      64
#define YB_OFF   101089984ull         // y bf16 [16384][768]           25,165,824
#define WS_NEED_YB (YB_OFF + 25165824ull)

__device__ __forceinline__ u16 f2bf(float f) {
  u32 u = __float_as_uint(f);
  u32 r = (u + 0x7FFFu + ((u >> 16) & 1u)) >> 16;
  return (u16)r;
}
__device__ __forceinline__ float bf2f(u16 v) {
  return __uint_as_float(((u32)v) << 16);
}

// fast GELU (tanh form via sigmoid): max |diff vs exact erf-GELU| ~3e-4 (validated R6)
__device__ __forceinline__ float gelu_f(float x) {
  float x3 = x * x * x;
  float t = -2.302208e0f * x - 1.0294817e-1f * x3;
  float e = __builtin_amdgcn_exp2f(t);
  return x * __builtin_amdgcn_rcpf(1.f + e);
}

// async global->LDS, 16B per lane. LDS dest must be wave-uniform; global src is per-lane.
__device__ __forceinline__ void gload16(const void* g, void* l) {
  __builtin_amdgcn_global_load_lds(
      (const __attribute__((address_space(1))) u32*)g,
      (__attribute__((address_space(3))) u32*)l, 16, 0, 0);
}

// XCD-chunked work swizzle (validated R11: FETCH -45%): bijective on [0,136).
__device__ __forceinline__ int xcd_swz(int x) { return (x & 7) * 17 + (x >> 3); }

// ---------------- fused prep: gating + both weight transposes (R15-proven) ----------------
__global__ __launch_bounds__(256)
void prep_kernel(const float* __restrict__ x, const float* __restrict__ Wg,
                 const float* __restrict__ bg, u16* __restrict__ xb,
                 int* __restrict__ tops, float* __restrict__ wts,
                 const float* __restrict__ W1, u16* __restrict__ w1t,
                 const float* __restrict__ W2, u16* __restrict__ w2t) {
  __shared__ u16 tile[64][65];
  const int bid = blockIdx.x;

  if (bid < PREP_GATE) {
    const int lane = threadIdx.x & 63;
    const int wv = threadIdx.x >> 6;
    const int t = bid * 4 + wv;
    float acc[8];
#pragma unroll
    for (int e = 0; e < 8; ++e) acc[e] = 0.f;
#pragma unroll
    for (int i = 0; i < 12; ++i) {
      int c = i * 64 + lane;
      float xv = x[(size_t)t * C_DIM + c];
      xb[(size_t)t * C_DIM + c] = f2bf(xv);
      const float4* wg4 = reinterpret_cast<const float4*>(Wg + c * 8);
      float4 wa = wg4[0], wb = wg4[1];
      acc[0] += xv * wa.x; acc[1] += xv * wa.y; acc[2] += xv * wa.z; acc[3] += xv * wa.w;
      acc[4] += xv * wb.x; acc[5] += xv * wb.y; acc[6] += xv * wb.z; acc[7] += xv * wb.w;
    }
#pragma unroll
    for (int off = 32; off > 0; off >>= 1) {
#pragma unroll
      for (int e = 0; e < 8; ++e) acc[e] += __shfl_xor(acc[e], off);
    }
    if (lane == 0) {
      float lg[8];
#pragma unroll
      for (int e = 0; e < 8; ++e) lg[e] = acc[e] + bg[e];
      int i1 = 0; float m1 = lg[0];
#pragma unroll
      for (int e = 1; e < 8; ++e) if (lg[e] > m1) { m1 = lg[e]; i1 = e; }
      int i2 = -1; float m2 = -3.4e38f;
#pragma unroll
      for (int e = 0; e < 8; ++e) if (e != i1 && lg[e] > m2) { m2 = lg[e]; i2 = e; }
      float rr = expf(m2 - m1);
      wts[2 * t] = 1.f / (1.f + rr);
      wts[2 * t + 1] = rr / (1.f + rr);
      tops[t] = i1 | (i2 << 4);
    }
    return;
  }

  const float* in;
  u16* out;
  int R, Cc, bx, by, e;
  if (bid < PREP_GATE + PREP_W1) {
    int idx = bid - PREP_GATE;
    in = W1; out = w1t; R = C_DIM; Cc = H_DIM;
    e = idx / 288; int rem = idx % 288;
    bx = rem % 24; by = rem / 24;
  } else {
    int idx = bid - PREP_GATE - PREP_W1;
    in = W2; out = w2t; R = H_DIM; Cc = C_DIM;
    e = idx / 288; int rem = idx % 288;
    bx = rem % 12; by = rem / 12;
  }
  const size_t base = (size_t)e * R * Cc;
  const int c0 = bx * 64;
  const int r0 = by * 64;
  for (int i = threadIdx.x; i < 64 * 64; i += 256) {
    int r = i >> 6, c = i & 63;
    tile[r][c] = f2bf(in[base + (size_t)(r0 + r) * Cc + c0 + c]);
  }
  __syncthreads();
  for (int i = threadIdx.x; i < 64 * 64; i += 256) {
    int cc = i >> 6, r = i & 63;
    out[base + (size_t)(c0 + cc) * R + r0 + r] = tile[r][cc];
  }
}

// ---------------- bucket build: deterministic counting sort + work-table ----------------
__global__ __launch_bounds__(1024)
void bucket_kernel(const int* __restrict__ tops, int* __restrict__ list,
                   int* __restrict__ pose, int* __restrict__ cnt, int* __restrict__ offs,
                   int* __restrict__ mtab, int* __restrict__ nblk) {
  __shared__ int v[8192];
  __shared__ int sums[1024];
  __shared__ int estart[9];
  const int tid = threadIdx.x;
#pragma unroll
  for (int k = 0; k < 8; ++k) v[k * 1024 + tid] = 0;
  int myt[8];
#pragma unroll
  for (int j = 0; j < 8; ++j) {          // 8 x 1024 = 8192 tokens
    int t = j * 1024 + tid;              // coalesced
    int tt = tops[t];
    myt[j] = tt;
    v[(tt & 15) * 1024 + tid]++;
    v[((tt >> 4) & 15) * 1024 + tid]++;
  }
  __syncthreads();
  int loc[8];
  int s = 0;
#pragma unroll
  for (int k = 0; k < 8; ++k) { loc[k] = s; s += v[tid * 8 + k]; }
  sums[tid] = s;
  __syncthreads();
  for (int off = 1; off < 1024; off <<= 1) {
    int a = sums[tid];
    int b = (tid >= off) ? sums[tid - off] : 0;
    __syncthreads();
    sums[tid] = a + b;
    __syncthreads();
  }
  int excl = (tid > 0) ? sums[tid - 1] : 0;
#pragma unroll
  for (int k = 0; k < 8; ++k) v[tid * 8 + k] = excl + loc[k];
  __syncthreads();
  if (tid < 8) estart[tid] = v[tid * 1024];
  if (tid == 0) estart[8] = 2 * T_TOK;
  __syncthreads();
#pragma unroll
  for (int k = 0; k < 8; ++k) v[k * 1024 + tid] -= estart[k];
  if (tid == 1023) {
    int c = 0;
    for (int e = 0; e < 8; ++e) {
      int te = estart[e + 1] - estart[e];
      for (int i = 0; i * 128 < te; ++i) mtab[c++] = (e << 8) | i;
    }
    nblk[0] = c;
  }
#pragma unroll
  for (int j = 0; j < 8; ++j) {
    int t = j * 1024 + tid;
    int tt = myt[j];
    int e1 = tt & 15, e2 = (tt >> 4) & 15;
    int p1 = v[e1 * 1024 + tid]++;
    list[e1 * T_TOK + p1] = 2 * t;
    pose[2 * t] = (e1 << 14) | p1;
    int p2 = v[e2 * 1024 + tid]++;
    list[e2 * T_TOK + p2] = 2 * t + 1;
    pose[2 * t + 1] = (e2 << 14) | p2;
  }
  if (tid < 8) {
    cnt[tid] = estart[tid + 1] - estart[tid];
    offs[tid] = estart[tid];
  }
}

// ---------------- grouped GEMM1: h = gelu(x[list] @ W1[e] + b1[e]) ----------------
// 128x192 tile, 4 waves (2Mx2N, per-wave 64x96 = 48 MFMA/K-step), dbuf,
// counted vmcnt(10). LDS exactly 81920B -> 2 blocks/CU. No toks LDS (direct loads).
__global__ __launch_bounds__(256)
void gemm1_kernel(const u16* __restrict__ xb, const u16* __restrict__ w1t,
                  const float* __restrict__ b1, u16* __restrict__ h,
                  const int* __restrict__ list, const int* __restrict__ cnt,
                  const int* __restrict__ offs, const int* __restrict__ mtab,
                  const int* __restrict__ nblk) {
  const int widx = xcd_swz((int)blockIdx.x);
  if (widx >= nblk[0]) return;
  const int ent = mtab[widx];
  const int e = ent >> 8;
  const int m0 = (ent & 255) * 128;
  const int Te = cnt[e];
  const int n0 = blockIdx.y * 192;
  const int tid = threadIdx.x;
  const int lane = tid & 63;
  const int wv = tid >> 6;
  const int wm = wv >> 1;
  const int wn = wv & 1;

  // u16 S: A0=[0,8192) A1=[8192,16384) B0=[16384,28672) B1=[28672,40960). 80KB exact.
  __shared__ __align__(16) u16 S[40960];

  const int rg = lane >> 3;
  const int unit = (lane & 7) ^ rg;
  const u16* ag[4];
  const u16* bgp[6];
#pragma unroll
  for (int i = 0; i < 4; ++i) {
    int row = (wv * 4 + i) * 8 + rg;     // A: 16 chunks cover 128 rows
    int p = m0 + row;
    if (p >= Te) p = Te - 1;
    int tok = list[e * T_TOK + p] >> 1;  // consumed before stage(0) -> vmcnt clean
    ag[i] = xb + (size_t)tok * C_DIM + unit * 8;
  }
#pragma unroll
  for (int i = 0; i < 6; ++i) {
    int row = (wv * 6 + i) * 8 + rg;     // B: 24 chunks cover 192 rows
    bgp[i] = w1t + ((size_t)e * H_DIM + n0 + row) * C_DIM + unit * 8;
  }
  __syncthreads();   // align waves at loop entry; drains pre-loop vmem

  f32x4 acc[4][6];
#pragma unroll
  for (int m = 0; m < 4; ++m)
#pragma unroll
    for (int n = 0; n < 6; ++n)
#pragma unroll
      for (int q = 0; q < 4; ++q) acc[m][n][q] = 0.f;

  const int r16 = lane & 15;
  const int kseg = lane >> 4;

  auto stage = [&](int kt, int buf) {
    const int k0 = kt * 64;
    const int abase = buf * 8192;
    const int bbase = 16384 + buf * 12288;
#pragma unroll
    for (int i = 0; i < 4; ++i) gload16(ag[i] + k0, &S[abase + (wv * 4 + i) * 512]);
#pragma unroll
    for (int i = 0; i < 6; ++i) gload16(bgp[i] + k0, &S[bbase + (wv * 6 + i) * 512]);
  };
  auto compute = [&](int cur) {
    const int abase = cur * 8192;
    const int bbase = 16384 + cur * 12288;
#pragma unroll
    for (int ks = 0; ks < 2; ++ks) {
      bf16x8 af[4], bb[6];
      const int un = ks * 4 + kseg;
#pragma unroll
      for (int m = 0; m < 4; ++m) {
        int arow = wm * 64 + m * 16 + r16;
        af[m] = *reinterpret_cast<const bf16x8*>(&S[abase + (arow * 8 + (un ^ (arow & 7))) * 8]);
      }
#pragma unroll
      for (int n = 0; n < 6; ++n) {
        int brow = wn * 96 + n * 16 + r16;
        bb[n] = *reinterpret_cast<const bf16x8*>(&S[bbase + (brow * 8 + (un ^ (brow & 7))) * 8]);
      }
#pragma unroll
      for (int m = 0; m < 4; ++m)
#pragma unroll
        for (int n = 0; n < 6; ++n)
          acc[m][n] = __builtin_amdgcn_mfma_f32_16x16x32_bf16(af[m], bb[n], acc[m][n], 0, 0, 0);
    }
  };

  const int NT = C_DIM / 64;  // 12
  stage(0, 0);
  for (int kt = 0; kt < NT - 1; ++kt) {
    const int cur = kt & 1;
    stage(kt + 1, cur ^ 1);                            // 10 loads in flight across barrier
    asm volatile("s_waitcnt vmcnt(10)" ::: "memory");  // oldest 10 (stage kt) landed
    __builtin_amdgcn_s_barrier();
    __builtin_amdgcn_sched_barrier(0);
    compute(cur);
    __builtin_amdgcn_s_barrier();
  }
  asm volatile("s_waitcnt vmcnt(0)" ::: "memory");
  __builtin_amdgcn_s_barrier();
  __builtin_amdgcn_sched_barrier(0);
  compute((NT - 1) & 1);
  __syncthreads();

  // epilogue: bias + fast GELU -> bf16 -> LDS (24-uint4 rows, XOR within 8-blocks)
  const int slot0 = offs[e] + m0;
  const int rb = (lane >> 4) * 4;
  float b1v[6];
#pragma unroll
  for (int n = 0; n < 6; ++n) b1v[n] = b1[e * H_DIM + n0 + wn * 96 + n * 16 + r16];
#pragma unroll
  for (int m = 0; m < 4; ++m) {
#pragma unroll
    for (int n = 0; n < 6; ++n) {
      int cl = wn * 96 + n * 16 + r16;
#pragma unroll
      for (int v = 0; v < 4; ++v) {
        int row = wm * 64 + m * 16 + rb + v;
        float val = gelu_f(acc[m][n][v] + b1v[n]);
        S[(row * 24 + ((cl >> 3) ^ (row & 7))) * 8 + (cl & 7)] = f2bf(val);
      }
    }
  }
  __syncthreads();
#pragma unroll
  for (int j = 0; j < 12; ++j) {
    int ulin = j * 256 + tid;            // 128 rows x 24 uint4 = 3072
    int row = ulin / 24;
    int uc = ulin % 24;
    if (m0 + row < Te) {
      uint4 vv = *reinterpret_cast<const uint4*>(&S[(row * 24 + (uc ^ (row & 7))) * 8]);
      *reinterpret_cast<uint4*>(&h[(size_t)(slot0 + row) * H_DIM + n0 + uc * 8]) = vv;
    }
  }
}

// ---------------- grouped GEMM2: y[slot] = h[slot] @ W2[e] + b2[e]  (y bf16) ----------------
// 128x192 tile, same structure; K=1536 (NT=24); N=768 -> 4 n-blocks.
__global__ __launch_bounds__(256)
void gemm2_kernel(const u16* __restrict__ h, const u16* __restrict__ w2t,
                  const float* __restrict__ b2, u16* __restrict__ yb,
                  const int* __restrict__ cnt, const int* __restrict__ offs,
                  const int* __restrict__ mtab, const int* __restrict__ nblk) {
  const int widx = xcd_swz((int)blockIdx.x);
  if (widx >= nblk[0]) return;
  const int ent = mtab[widx];
  const int e = ent >> 8;
  const int m0 = (ent & 255) * 128;
  const int Te = cnt[e];
  const int n0 = blockIdx.y * 192;
  const int tid = threadIdx.x;
  const int lane = tid & 63;
  const int wv = tid >> 6;
  const int wm = wv >> 1;
  const int wn = wv & 1;
  const int base = offs[e];

  __shared__ __align__(16) u16 S[40960];

  const int rg = lane >> 3;
  const int unit = (lane & 7) ^ rg;
  const u16* ag[4];
  const u16* bgp[6];
#pragma unroll
  for (int i = 0; i < 4; ++i) {
    int row = (wv * 4 + i) * 8 + rg;
    int p = m0 + row;
    if (p >= Te) p = Te - 1;
    ag[i] = h + (size_t)(base + p) * H_DIM + unit * 8;
  }
#pragma unroll
  for (int i = 0; i < 6; ++i) {
    int row = (wv * 6 + i) * 8 + rg;
    bgp[i] = w2t + ((size_t)e * C_DIM + n0 + row) * H_DIM + unit * 8;
  }
  __syncthreads();

  f32x4 acc[4][6];
#pragma unroll
  for (int m = 0; m < 4; ++m)
#pragma unroll
    for (int n = 0; n < 6; ++n)
#pragma unroll
      for (int q = 0; q < 4; ++q) acc[m][n][q] = 0.f;

  const int r16 = lane & 15;
  const int kseg = lane >> 4;

  auto stage = [&](int kt, int buf) {
    const int k0 = kt * 64;
    const int abase = buf * 8192;
    const int bbase = 16384 + buf * 12288;
#pragma unroll
    for (int i = 0; i < 4; ++i) gload16(ag[i] + k0, &S[abase + (wv * 4 + i) * 512]);
#pragma unroll
    for (int i = 0; i < 6; ++i) gload16(bgp[i] + k0, &S[bbase + (wv * 6 + i) * 512]);
  };
  auto compute = [&](int cur) {
    const int abase = cur * 8192;
    const int bbase = 16384 + cur * 12288;
#pragma unroll
    for (int ks = 0; ks < 2; ++ks) {
      bf16x8 af[4], bb[6];
      const int un = ks * 4 + kseg;
#pragma unroll
      for (int m = 0; m < 4; ++m) {
        int arow = wm * 64 + m * 16 + r16;
        af[m] = *reinterpret_cast<const bf16x8*>(&S[abase + (arow * 8 + (un ^ (arow & 7))) * 8]);
      }
#pragma unroll
      for (int n = 0; n < 6; ++n) {
        int brow = wn * 96 + n * 16 + r16;
        bb[n] = *reinterpret_cast<const bf16x8*>(&S[bbase + (brow * 8 + (un ^ (brow & 7))) * 8]);
      }
#pragma unroll
      for (int m = 0; m < 4; ++m)
#pragma unroll
        for (int n = 0; n < 6; ++n)
          acc[m][n] = __builtin_amdgcn_mfma_f32_16x16x32_bf16(af[m], bb[n], acc[m][n], 0, 0, 0);
    }
  };

  const int NT = H_DIM / 64;  // 24
  stage(0, 0);
  for (int kt = 0; kt < NT - 1; ++kt) {
    const int cur = kt & 1;
    stage(kt + 1, cur ^ 1);
    asm volatile("s_waitcnt vmcnt(10)" ::: "memory");
    __builtin_amdgcn_s_barrier();
    __builtin_amdgcn_sched_barrier(0);
    compute(cur);
    __builtin_amdgcn_s_barrier();
  }
  asm volatile("s_waitcnt vmcnt(0)" ::: "memory");
  __builtin_amdgcn_s_barrier();
  __builtin_amdgcn_sched_barrier(0);
  compute((NT - 1) & 1);
  __syncthreads();

  // epilogue: bias -> bf16 -> LDS (24-uint4 rows) -> coalesced 16B stores
  const int rb = (lane >> 4) * 4;
  float b2v[6];
#pragma unroll
  for (int n = 0; n < 6; ++n) b2v[n] = b2[e * C_DIM + n0 + wn * 96 + n * 16 + r16];
#pragma unroll
  for (int m = 0; m < 4; ++m) {
#pragma unroll
    for (int n = 0; n < 6; ++n) {
      int cl = wn * 96 + n * 16 + r16;
#pragma unroll
      for (int v = 0; v < 4; ++v) {
        int row = wm * 64 + m * 16 + rb + v;
        S[(row * 24 + ((cl >> 3) ^ (row & 7))) * 8 + (cl & 7)] = f2bf(acc[m][n][v] + b2v[n]);
      }
    }
  }
  __syncthreads();
#pragma unroll
  for (int j = 0; j < 12; ++j) {
    int ulin = j * 256 + tid;
    int row = ulin / 24;
    int uc = ulin % 24;
    if (m0 + row < Te) {
      uint4 vv = *reinterpret_cast<const uint4*>(&S[(row * 24 + (uc ^ (row & 7))) * 8]);
      *reinterpret_cast<uint4*>(&yb[(size_t)(base + m0 + row) * C_DIM + n0 + uc * 8]) = vv;
    }
  }
}

// ---------------- combine: out[t] = w0*y[slot0] + w1*y[slot1] (y bf16) ----------------
__global__ void combine_kernel(const u16* __restrict__ yb, const int* __restrict__ pose,
                               const float* __restrict__ wts, const int* __restrict__ offs,
                               float* __restrict__ out) {
  const int wv = threadIdx.x >> 6;
  const int lane = threadIdx.x & 63;
  const int t = blockIdx.x * 4 + wv;
  int p0 = pose[2 * t], p1 = pose[2 * t + 1];
  size_t s0 = (size_t)offs[p0 >> 14] + (p0 & 16383);
  size_t s1 = (size_t)offs[p1 >> 14] + (p1 & 16383);
  float w0 = wts[2 * t], w1 = wts[2 * t + 1];
  float4* o = reinterpret_cast<float4*>(out + (size_t)t * C_DIM);
  const uint4* ya = reinterpret_cast<const uint4*>(yb + s0 * C_DIM);
  const uint4* yc = reinterpret_cast<const uint4*>(yb + s1 * C_DIM);
#pragma unroll
  for (int j = 0; j < 2; ++j) {
    int c = j * 64 + lane;
    if (c < 96) {                      // 96 uint4 (16B) per 768-col row
      uint4 a = ya[c], b = yc[c];
      float4 o0, o1;
      o0.x = w0 * bf2f((u16)(a.x & 0xFFFF)) + w1 * bf2f((u16)(b.x & 0xFFFF));
      o0.y = w0 * bf2f((u16)(a.x >> 16))    + w1 * bf2f((u16)(b.x >> 16));
      o0.z = w0 * bf2f((u16)(a.y & 0xFFFF)) + w1 * bf2f((u16)(b.y & 0xFFFF));
      o0.w = w0 * bf2f((u16)(a.y >> 16))    + w1 * bf2f((u16)(b.y >> 16));
      o1.x = w0 * bf2f((u16)(a.z & 0xFFFF)) + w1 * bf2f((u16)(b.z & 0xFFFF));
      o1.y = w0 * bf2f((u16)(a.z >> 16))    + w1 * bf2f((u16)(b.z >> 16));
      o1.z = w0 * bf2f((u16)(a.w & 0xFFFF)) + w1 * bf2f((u16)(b.w & 0xFFFF));
      o1.w = w0 * bf2f((u16)(a.w >> 16))    + w1 * bf2f((u16)(b.w >> 16));
      o[2 * c] = o0;
      o[2 * c + 1] = o1;
    }
  }
}

extern "C" void kernel_launch(void* const* d_in, const int* in_sizes, int n_in,
                              void* d_out, int out_size, void* d_ws, size_t ws_size,
                              hipStream_t stream) {
  const float* x  = (const float*)d_in[0];
  const float* Wg = (const float*)d_in[1];
  const float* bg = (const float*)d_in[2];
  const float* W1 = (const float*)d_in[3];
  const float* b1 = (const float*)d_in[4];
  const float* W2 = (const float*)d_in[5];
  const float* b2 = (const float*)d_in[6];
  float* out = (float*)d_out;

  char* ws = (char*)d_ws;
  u16*   xb   = (u16*)(ws + XB_OFF);
  u16*   w1t  = (u16*)(ws + W1T_OFF);
  u16*   w2t  = (u16*)(ws + W2T_OFF);
  u16*   h    = (u16*)(ws + H_OFF);
  int*   list = (int*)(ws + LIST_OFF);
  float* wts  = (float*)(ws + WTS_OFF);
  int*   pose = (int*)(ws + POSE_OFF);
  int*   cnt  = (int*)(ws + CNT_OFF);
  int*   offs = (int*)(ws + OFFS_OFF);
  int*   tops = (int*)(ws + TOPS_OFF);
  int*   mtab = (int*)(ws + MTAB_OFF);
  int*   nblk = (int*)(ws + NBLK_OFF);
  u16*   yb   = (ws_size >= WS_NEED_YB) ? (u16*)(ws + YB_OFF) : (u16*)(ws + XB_OFF);

  prep_kernel<<<PREP_NBLK, 256, 0, stream>>>(x, Wg, bg, xb, tops, wts, W1, w1t, W2, w2t);
  bucket_kernel<<<1, 1024, 0, stream>>>(tops, list, pose, cnt, offs, mtab, nblk);
  gemm1_kernel<<<dim3(MAXBLK, H_DIM / 192, 1), 256, 0, stream>>>(xb, w1t, b1, h, list, cnt, offs, mtab, nblk);
  gemm2_kernel<<<dim3(MAXBLK, C_DIM / 192, 1), 256, 0, stream>>>(h, w2t, b2, yb, cnt, offs, mtab, nblk);
  combine_kernel<<<T_TOK / 4, 256, 0, stream>>>(yb, pose, wts, offs, out);
}

// Round 18
// 168.285 us; speedup vs baseline: 1.4030x; 1.4030x over previous
//
#include <hip/hip_runtime.h>
#include <hip/hip_bf16.h>

// MoE top-2: B=8,N=1024,C=768,E=8,H=1536. Tokens T=8192, assignments=16384.
typedef unsigned short u16;
typedef unsigned int u32;
typedef __bf16 bf16x8 __attribute__((ext_vector_type(8)));
typedef float f32x4 __attribute__((ext_vector_type(4)));

#define T_TOK 8192
#define C_DIM 768
#define E_DIM 8
#define H_DIM 1536
#define MAXBLK 136   // = 8 XCDs * 17; >= max Σ ceil(cnt[e]/128) = 135

// prep fusion: [0,2048) gating, [2048,4352) W1-transpose, [4352,6656) W2-transpose
#define PREP_GATE 2048
#define PREP_W1   2304
#define PREP_NBLK (PREP_GATE + 2 * PREP_W1)

// ---- ws layout (bytes) ----
#define XB_OFF   0ull                 // x bf16 [8192][768]           12,582,912
#define W1T_OFF  12582912ull          // W1^T bf16 [E][H][C]          18,874,368
#define W2T_OFF  31457280ull          // W2^T bf16 [E][C][H]          18,874,368
#define H_OFF    50331648ull          // h bf16 [16384][1536]         50,331,648
#define LIST_OFF 100663296ull         // int [E][8192] entry=2*tok+rank
#define WTS_OFF  100925440ull         // float [16384]
#define POSE_OFF 100990976ull         // int [16384]: (e<<14)|pos
#define CNT_OFF  101056512ull         // int [8]
#define OFFS_OFF 101056544ull         // int [8]
#define TOPS_OFF 101056576ull         // int [8192]: i1 | (i2<<4)      32,768
#define MTAB_OFF 101089344ull         // int [144]: (e<<8)|m_chunk     576
#define NBLK_OFF 101089920ull         // int [16]                      64
#define YB_OFF   101089984ull         // y bf16 [16384][768]           25,165,824
#define WS_NEED_YB (YB_OFF + 25165824ull)

__device__ __forceinline__ u16 f2bf(float f) {
  u32 u = __float_as_uint(f);
  u32 r = (u + 0x7FFFu + ((u >> 16) & 1u)) >> 16;
  return (u16)r;
}
__device__ __forceinline__ float bf2f(u16 v) {
  return __uint_as_float(((u32)v) << 16);
}

// fast GELU (tanh form via sigmoid): max |diff vs exact erf-GELU| ~3e-4 (validated R6)
__device__ __forceinline__ float gelu_f(float x) {
  float x3 = x * x * x;
  float t = -2.302208e0f * x - 1.0294817e-1f * x3;
  float e = __builtin_amdgcn_exp2f(t);
  return x * __builtin_amdgcn_rcpf(1.f + e);
}

// async global->LDS, 16B per lane. LDS dest must be wave-uniform; global src is per-lane.
__device__ __forceinline__ void gload16(const void* g, void* l) {
  __builtin_amdgcn_global_load_lds(
      (const __attribute__((address_space(1))) u32*)g,
      (__attribute__((address_space(3))) u32*)l, 16, 0, 0);
}

// XCD-chunked work swizzle (validated R11: FETCH -45%): bijective on [0,136).
__device__ __forceinline__ int xcd_swz(int x) { return (x & 7) * 17 + (x >> 3); }

// ---------------- fused prep: gating + both weight transposes (R15-proven) ----------------
__global__ __launch_bounds__(256)
void prep_kernel(const float* __restrict__ x, const float* __restrict__ Wg,
                 const float* __restrict__ bg, u16* __restrict__ xb,
                 int* __restrict__ tops, float* __restrict__ wts,
                 const float* __restrict__ W1, u16* __restrict__ w1t,
                 const float* __restrict__ W2, u16* __restrict__ w2t) {
  __shared__ u16 tile[64][65];
  const int bid = blockIdx.x;

  if (bid < PREP_GATE) {
    const int lane = threadIdx.x & 63;
    const int wv = threadIdx.x >> 6;
    const int t = bid * 4 + wv;
    float acc[8];
#pragma unroll
    for (int e = 0; e < 8; ++e) acc[e] = 0.f;
#pragma unroll
    for (int i = 0; i < 12; ++i) {
      int c = i * 64 + lane;
      float xv = x[(size_t)t * C_DIM + c];
      xb[(size_t)t * C_DIM + c] = f2bf(xv);
      const float4* wg4 = reinterpret_cast<const float4*>(Wg + c * 8);
      float4 wa = wg4[0], wb = wg4[1];
      acc[0] += xv * wa.x; acc[1] += xv * wa.y; acc[2] += xv * wa.z; acc[3] += xv * wa.w;
      acc[4] += xv * wb.x; acc[5] += xv * wb.y; acc[6] += xv * wb.z; acc[7] += xv * wb.w;
    }
#pragma unroll
    for (int off = 32; off > 0; off >>= 1) {
#pragma unroll
      for (int e = 0; e < 8; ++e) acc[e] += __shfl_xor(acc[e], off);
    }
    if (lane == 0) {
      float lg[8];
#pragma unroll
      for (int e = 0; e < 8; ++e) lg[e] = acc[e] + bg[e];
      int i1 = 0; float m1 = lg[0];
#pragma unroll
      for (int e = 1; e < 8; ++e) if (lg[e] > m1) { m1 = lg[e]; i1 = e; }
      int i2 = -1; float m2 = -3.4e38f;
#pragma unroll
      for (int e = 0; e < 8; ++e) if (e != i1 && lg[e] > m2) { m2 = lg[e]; i2 = e; }
      float rr = expf(m2 - m1);
      wts[2 * t] = 1.f / (1.f + rr);
      wts[2 * t + 1] = rr / (1.f + rr);
      tops[t] = i1 | (i2 << 4);
    }
    return;
  }

  const float* in;
  u16* out;
  int R, Cc, bx, by, e;
  if (bid < PREP_GATE + PREP_W1) {
    int idx = bid - PREP_GATE;
    in = W1; out = w1t; R = C_DIM; Cc = H_DIM;
    e = idx / 288; int rem = idx % 288;
    bx = rem % 24; by = rem / 24;
  } else {
    int idx = bid - PREP_GATE - PREP_W1;
    in = W2; out = w2t; R = H_DIM; Cc = C_DIM;
    e = idx / 288; int rem = idx % 288;
    bx = rem % 12; by = rem / 12;
  }
  const size_t base = (size_t)e * R * Cc;
  const int c0 = bx * 64;
  const int r0 = by * 64;
  for (int i = threadIdx.x; i < 64 * 64; i += 256) {
    int r = i >> 6, c = i & 63;
    tile[r][c] = f2bf(in[base + (size_t)(r0 + r) * Cc + c0 + c]);
  }
  __syncthreads();
  for (int i = threadIdx.x; i < 64 * 64; i += 256) {
    int cc = i >> 6, r = i & 63;
    out[base + (size_t)(c0 + cc) * R + r0 + r] = tile[r][cc];
  }
}

// ---------------- bucket build: deterministic counting sort + work-table ----------------
__global__ __launch_bounds__(1024)
void bucket_kernel(const int* __restrict__ tops, int* __restrict__ list,
                   int* __restrict__ pose, int* __restrict__ cnt, int* __restrict__ offs,
                   int* __restrict__ mtab, int* __restrict__ nblk) {
  __shared__ int v[8192];
  __shared__ int sums[1024];
  __shared__ int estart[9];
  const int tid = threadIdx.x;
#pragma unroll
  for (int k = 0; k < 8; ++k) v[k * 1024 + tid] = 0;
  int myt[8];
#pragma unroll
  for (int j = 0; j < 8; ++j) {          // 8 x 1024 = 8192 tokens
    int t = j * 1024 + tid;              // coalesced
    int tt = tops[t];
    myt[j] = tt;
    v[(tt & 15) * 1024 + tid]++;
    v[((tt >> 4) & 15) * 1024 + tid]++;
  }
  __syncthreads();
  int loc[8];
  int s = 0;
#pragma unroll
  for (int k = 0; k < 8; ++k) { loc[k] = s; s += v[tid * 8 + k]; }
  sums[tid] = s;
  __syncthreads();
  for (int off = 1; off < 1024; off <<= 1) {
    int a = sums[tid];
    int b = (tid >= off) ? sums[tid - off] : 0;
    __syncthreads();
    sums[tid] = a + b;
    __syncthreads();
  }
  int excl = (tid > 0) ? sums[tid - 1] : 0;
#pragma unroll
  for (int k = 0; k < 8; ++k) v[tid * 8 + k] = excl + loc[k];
  __syncthreads();
  if (tid < 8) estart[tid] = v[tid * 1024];
  if (tid == 0) estart[8] = 2 * T_TOK;
  __syncthreads();
#pragma unroll
  for (int k = 0; k < 8; ++k) v[k * 1024 + tid] -= estart[k];
  if (tid == 1023) {
    int c = 0;
    for (int e = 0; e < 8; ++e) {
      int te = estart[e + 1] - estart[e];
      for (int i = 0; i * 128 < te; ++i) mtab[c++] = (e << 8) | i;
    }
    nblk[0] = c;
  }
#pragma unroll
  for (int j = 0; j < 8; ++j) {
    int t = j * 1024 + tid;
    int tt = myt[j];
    int e1 = tt & 15, e2 = (tt >> 4) & 15;
    int p1 = v[e1 * 1024 + tid]++;
    list[e1 * T_TOK + p1] = 2 * t;
    pose[2 * t] = (e1 << 14) | p1;
    int p2 = v[e2 * 1024 + tid]++;
    list[e2 * T_TOK + p2] = 2 * t + 1;
    pose[2 * t + 1] = (e2 << 14) | p2;
  }
  if (tid < 8) {
    cnt[tid] = estart[tid + 1] - estart[tid];
    offs[tid] = estart[tid];
  }
}

// ---------------- grouped GEMM1: h = gelu(x[list] @ W1[e] + b1[e]) ----------------
// R11 structure exactly: 128x128, 4 waves, dbuf, counted vmcnt(8), inline swizzle.
__global__ __launch_bounds__(256)
void gemm1_kernel(const u16* __restrict__ xb, const u16* __restrict__ w1t,
                  const float* __restrict__ b1, u16* __restrict__ h,
                  const int* __restrict__ list, const int* __restrict__ cnt,
                  const int* __restrict__ offs, const int* __restrict__ mtab,
                  const int* __restrict__ nblk) {
  const int widx = xcd_swz((int)blockIdx.x);
  if (widx >= nblk[0]) return;
  const int ent = mtab[widx];
  const int e = ent >> 8;
  const int m0 = (ent & 255) * 128;
  const int Te = cnt[e];
  const int n0 = blockIdx.y * 128;
  const int tid = threadIdx.x;
  const int lane = tid & 63;
  const int wv = tid >> 6;
  const int wm = wv >> 1;
  const int wn = wv & 1;

  __shared__ __align__(16) u16 S[32768];  // A0 A1 B0 B1, 8K u16 each
  __shared__ int toks[128];

  if (tid < 128) {
    int p = m0 + tid;
    toks[tid] = list[e * T_TOK + ((p < Te) ? p : (Te - 1))] >> 1;
  }
  __syncthreads();   // drains pre-loop vmem -> vmcnt bookkeeping starts at 0

  const int rg = lane >> 3;
  const int unit = (lane & 7) ^ rg;
  const u16* ag[4];
  const u16* bgp[4];
#pragma unroll
  for (int i = 0; i < 4; ++i) {
    int row = (wv * 4 + i) * 8 + rg;
    ag[i] = xb + (size_t)toks[row] * C_DIM + unit * 8;
    bgp[i] = w1t + ((size_t)e * H_DIM + n0 + row) * C_DIM + unit * 8;
  }

  f32x4 acc[4][4];
#pragma unroll
  for (int m = 0; m < 4; ++m)
#pragma unroll
    for (int n = 0; n < 4; ++n)
#pragma unroll
      for (int q = 0; q < 4; ++q) acc[m][n][q] = 0.f;

  const int r16 = lane & 15;
  const int kseg = lane >> 4;

  auto stage = [&](int kt, int buf) {
    const int k0 = kt * 64;
    const int abase = buf * 8192;
    const int bbase = 16384 + buf * 8192;
#pragma unroll
    for (int i = 0; i < 4; ++i) gload16(ag[i] + k0, &S[abase + (wv * 4 + i) * 512]);
#pragma unroll
    for (int i = 0; i < 4; ++i) gload16(bgp[i] + k0, &S[bbase + (wv * 4 + i) * 512]);
  };
  auto compute = [&](int cur) {
    const int abase = cur * 8192;
    const int bbase = 16384 + cur * 8192;
#pragma unroll
    for (int ks = 0; ks < 2; ++ks) {
      bf16x8 af[4], bb[4];
      const int un = ks * 4 + kseg;
#pragma unroll
      for (int m = 0; m < 4; ++m) {
        int arow = wm * 64 + m * 16 + r16;
        af[m] = *reinterpret_cast<const bf16x8*>(&S[abase + (arow * 8 + (un ^ (arow & 7))) * 8]);
      }
#pragma unroll
      for (int n = 0; n < 4; ++n) {
        int brow = wn * 64 + n * 16 + r16;
        bb[n] = *reinterpret_cast<const bf16x8*>(&S[bbase + (brow * 8 + (un ^ (brow & 7))) * 8]);
      }
#pragma unroll
      for (int m = 0; m < 4; ++m)
#pragma unroll
        for (int n = 0; n < 4; ++n)
          acc[m][n] = __builtin_amdgcn_mfma_f32_16x16x32_bf16(af[m], bb[n], acc[m][n], 0, 0, 0);
    }
  };

  const int NT = C_DIM / 64;  // 12
  stage(0, 0);
  for (int kt = 0; kt < NT - 1; ++kt) {
    const int cur = kt & 1;
    stage(kt + 1, cur ^ 1);                           // 8 loads in flight across barrier
    asm volatile("s_waitcnt vmcnt(8)" ::: "memory");  // oldest 8 (stage kt) landed
    __builtin_amdgcn_s_barrier();
    __builtin_amdgcn_sched_barrier(0);
    compute(cur);
    __builtin_amdgcn_s_barrier();
  }
  asm volatile("s_waitcnt vmcnt(0)" ::: "memory");
  __builtin_amdgcn_s_barrier();
  __builtin_amdgcn_sched_barrier(0);
  compute((NT - 1) & 1);
  __syncthreads();

  // epilogue: bias + fast GELU -> bf16 -> LDS (swizzled) -> coalesced 16B stores
  const int slot0 = offs[e] + m0;
  const int rb = (lane >> 4) * 4;
  float b1v[4];
#pragma unroll
  for (int n = 0; n < 4; ++n) b1v[n] = b1[e * H_DIM + n0 + wn * 64 + n * 16 + r16];
#pragma unroll
  for (int m = 0; m < 4; ++m) {
#pragma unroll
    for (int n = 0; n < 4; ++n) {
      int cl = wn * 64 + n * 16 + r16;
#pragma unroll
      for (int v = 0; v < 4; ++v) {
        int row = wm * 64 + m * 16 + rb + v;
        float val = gelu_f(acc[m][n][v] + b1v[n]);
        S[(row * 16 + ((cl >> 3) ^ (row & 15))) * 8 + (cl & 7)] = f2bf(val);
      }
    }
  }
  __syncthreads();
#pragma unroll
  for (int j = 0; j < 8; ++j) {
    int ulin = j * 256 + tid;
    int row = ulin >> 4;
    int uc = ulin & 15;
    if (m0 + row < Te) {
      uint4 vv = *reinterpret_cast<const uint4*>(&S[(row * 16 + (uc ^ (row & 15))) * 8]);
      *reinterpret_cast<uint4*>(&h[(size_t)(slot0 + row) * H_DIM + n0 + uc * 8]) = vv;
    }
  }
}

// ---------------- grouped GEMM2: y[slot] = h[slot] @ W2[e] + b2[e]  (y in bf16) ----------------
__global__ __launch_bounds__(256)
void gemm2_kernel(const u16* __restrict__ h, const u16* __restrict__ w2t,
                  const float* __restrict__ b2, u16* __restrict__ yb,
                  const int* __restrict__ cnt, const int* __restrict__ offs,
                  const int* __restrict__ mtab, const int* __restrict__ nblk) {
  const int widx = xcd_swz((int)blockIdx.x);
  if (widx >= nblk[0]) return;
  const int ent = mtab[widx];
  const int e = ent >> 8;
  const int m0 = (ent & 255) * 128;
  const int Te = cnt[e];
  const int n0 = blockIdx.y * 128;
  const int tid = threadIdx.x;
  const int lane = tid & 63;
  const int wv = tid >> 6;
  const int wm = wv >> 1;
  const int wn = wv & 1;
  const int base = offs[e];

  __shared__ __align__(16) u16 S[32768];

  const int rg = lane >> 3;
  const int unit = (lane & 7) ^ rg;
  const u16* ag[4];
  const u16* bgp[4];
#pragma unroll
  for (int i = 0; i < 4; ++i) {
    int row = (wv * 4 + i) * 8 + rg;
    int p = m0 + row;
    if (p >= Te) p = Te - 1;
    ag[i] = h + (size_t)(base + p) * H_DIM + unit * 8;
    bgp[i] = w2t + ((size_t)e * C_DIM + n0 + row) * H_DIM + unit * 8;
  }
  __syncthreads();  // drain pre-loop vmem -> clean vmcnt

  f32x4 acc[4][4];
#pragma unroll
  for (int m = 0; m < 4; ++m)
#pragma unroll
    for (int n = 0; n < 4; ++n)
#pragma unroll
      for (int q = 0; q < 4; ++q) acc[m][n][q] = 0.f;

  const int r16 = lane & 15;
  const int kseg = lane >> 4;

  auto stage = [&](int kt, int buf) {
    const int k0 = kt * 64;
    const int abase = buf * 8192;
    const int bbase = 16384 + buf * 8192;
#pragma unroll
    for (int i = 0; i < 4; ++i) gload16(ag[i] + k0, &S[abase + (wv * 4 + i) * 512]);
#pragma unroll
    for (int i = 0; i < 4; ++i) gload16(bgp[i] + k0, &S[bbase + (wv * 4 + i) * 512]);
  };
  auto compute = [&](int cur) {
    const int abase = cur * 8192;
    const int bbase = 16384 + cur * 8192;
#pragma unroll
    for (int ks = 0; ks < 2; ++ks) {
      bf16x8 af[4], bb[4];
      const int un = ks * 4 + kseg;
#pragma unroll
      for (int m = 0; m < 4; ++m) {
        int arow = wm * 64 + m * 16 + r16;
        af[m] = *reinterpret_cast<const bf16x8*>(&S[abase + (arow * 8 + (un ^ (arow & 7))) * 8]);
      }
#pragma unroll
      for (int n = 0; n < 4; ++n) {
        int brow = wn * 64 + n * 16 + r16;
        bb[n] = *reinterpret_cast<const bf16x8*>(&S[bbase + (brow * 8 + (un ^ (brow & 7))) * 8]);
      }
#pragma unroll
      for (int m = 0; m < 4; ++m)
#pragma unroll
        for (int n = 0; n < 4; ++n)
          acc[m][n] = __builtin_amdgcn_mfma_f32_16x16x32_bf16(af[m], bb[n], acc[m][n], 0, 0, 0);
    }
  };

  const int NT = H_DIM / 64;  // 24
  stage(0, 0);
  for (int kt = 0; kt < NT - 1; ++kt) {
    const int cur = kt & 1;
    stage(kt + 1, cur ^ 1);
    asm volatile("s_waitcnt vmcnt(8)" ::: "memory");
    __builtin_amdgcn_s_barrier();
    __builtin_amdgcn_sched_barrier(0);
    compute(cur);
    __builtin_amdgcn_s_barrier();
  }
  asm volatile("s_waitcnt vmcnt(0)" ::: "memory");
  __builtin_amdgcn_s_barrier();
  __builtin_amdgcn_sched_barrier(0);
  compute((NT - 1) & 1);
  __syncthreads();

  // epilogue: bias -> bf16 -> LDS (swizzled) -> coalesced 16B stores
  const int rb = (lane >> 4) * 4;
  float b2v[4];
#pragma unroll
  for (int n = 0; n < 4; ++n) b2v[n] = b2[e * C_DIM + n0 + wn * 64 + n * 16 + r16];
#pragma unroll
  for (int m = 0; m < 4; ++m) {
#pragma unroll
    for (int n = 0; n < 4; ++n) {
      int cl = wn * 64 + n * 16 + r16;
#pragma unroll
      for (int v = 0; v < 4; ++v) {
        int row = wm * 64 + m * 16 + rb + v;
        S[(row * 16 + ((cl >> 3) ^ (row & 15))) * 8 + (cl & 7)] = f2bf(acc[m][n][v] + b2v[n]);
      }
    }
  }
  __syncthreads();
#pragma unroll
  for (int j = 0; j < 8; ++j) {
    int ulin = j * 256 + tid;
    int row = ulin >> 4;
    int uc = ulin & 15;
    if (m0 + row < Te) {
      uint4 vv = *reinterpret_cast<const uint4*>(&S[(row * 16 + (uc ^ (row & 15))) * 8]);
      *reinterpret_cast<uint4*>(&yb[(size_t)(base + m0 + row) * C_DIM + n0 + uc * 8]) = vv;
    }
  }
}

// ---------------- combine: out[t] = w0*y[slot0] + w1*y[slot1] (y bf16) ----------------
__global__ void combine_kernel(const u16* __restrict__ yb, const int* __restrict__ pose,
                               const float* __restrict__ wts, const int* __restrict__ offs,
                               float* __restrict__ out) {
  const int wv = threadIdx.x >> 6;
  const int lane = threadIdx.x & 63;
  const int t = blockIdx.x * 4 + wv;
  int p0 = pose[2 * t], p1 = pose[2 * t + 1];
  size_t s0 = (size_t)offs[p0 >> 14] + (p0 & 16383);
  size_t s1 = (size_t)offs[p1 >> 14] + (p1 & 16383);
  float w0 = wts[2 * t], w1 = wts[2 * t + 1];
  float4* o = reinterpret_cast<float4*>(out + (size_t)t * C_DIM);
  const uint4* ya = reinterpret_cast<const uint4*>(yb + s0 * C_DIM);
  const uint4* yc = reinterpret_cast<const uint4*>(yb + s1 * C_DIM);
#pragma unroll
  for (int j = 0; j < 2; ++j) {
    int c = j * 64 + lane;
    if (c < 96) {                      // 96 uint4 (16B) per 768-col row
      uint4 a = ya[c], b = yc[c];
      float4 o0, o1;
      o0.x = w0 * bf2f((u16)(a.x & 0xFFFF)) + w1 * bf2f((u16)(b.x & 0xFFFF));
      o0.y = w0 * bf2f((u16)(a.x >> 16))    + w1 * bf2f((u16)(b.x >> 16));
      o0.z = w0 * bf2f((u16)(a.y & 0xFFFF)) + w1 * bf2f((u16)(b.y & 0xFFFF));
      o0.w = w0 * bf2f((u16)(a.y >> 16))    + w1 * bf2f((u16)(b.y >> 16));
      o1.x = w0 * bf2f((u16)(a.z & 0xFFFF)) + w1 * bf2f((u16)(b.z & 0xFFFF));
      o1.y = w0 * bf2f((u16)(a.z >> 16))    + w1 * bf2f((u16)(b.z >> 16));
      o1.z = w0 * bf2f((u16)(a.w & 0xFFFF)) + w1 * bf2f((u16)(b.w & 0xFFFF));
      o1.w = w0 * bf2f((u16)(a.w >> 16))    + w1 * bf2f((u16)(b.w >> 16));
      o[2 * c] = o0;
      o[2 * c + 1] = o1;
    }
  }
}

extern "C" void kernel_launch(void* const* d_in, const int* in_sizes, int n_in,
                              void* d_out, int out_size, void* d_ws, size_t ws_size,
                              hipStream_t stream) {
  const float* x  = (const float*)d_in[0];
  const float* Wg = (const float*)d_in[1];
  const float* bg = (const float*)d_in[2];
  const float* W1 = (const float*)d_in[3];
  const float* b1 = (const float*)d_in[4];
  const float* W2 = (const float*)d_in[5];
  const float* b2 = (const float*)d_in[6];
  float* out = (float*)d_out;

  char* ws = (char*)d_ws;
  u16*   xb   = (u16*)(ws + XB_OFF);
  u16*   w1t  = (u16*)(ws + W1T_OFF);
  u16*   w2t  = (u16*)(ws + W2T_OFF);
  u16*   h    = (u16*)(ws + H_OFF);
  int*   list = (int*)(ws + LIST_OFF);
  float* wts  = (float*)(ws + WTS_OFF);
  int*   pose = (int*)(ws + POSE_OFF);
  int*   cnt  = (int*)(ws + CNT_OFF);
  int*   offs = (int*)(ws + OFFS_OFF);
  int*   tops = (int*)(ws + TOPS_OFF);
  int*   mtab = (int*)(ws + MTAB_OFF);
  int*   nblk = (int*)(ws + NBLK_OFF);
  u16*   yb   = (ws_size >= WS_NEED_YB) ? (u16*)(ws + YB_OFF) : (u16*)(ws + XB_OFF);

  prep_kernel<<<PREP_NBLK, 256, 0, stream>>>(x, Wg, bg, xb, tops, wts, W1, w1t, W2, w2t);
  bucket_kernel<<<1, 1024, 0, stream>>>(tops, list, pose, cnt, offs, mtab, nblk);
  gemm1_kernel<<<dim3(MAXBLK, H_DIM / 128, 1), 256, 0, stream>>>(xb, w1t, b1, h, list, cnt, offs, mtab, nblk);
  gemm2_kernel<<<dim3(MAXBLK, C_DIM / 128, 1), 256, 0, stream>>>(h, w2t, b2, yb, cnt, offs, mtab, nblk);
  combine_kernel<<<T_TOK / 4, 256, 0, stream>>>(yb, pose, wts, offs, out);
}